// Round 1
// baseline (163.064 us; speedup 1.0000x reference)
//
#include <hip/hip_runtime.h>
#include <math.h>

// ---------------- problem constants ----------------
#define NAGT 4096          // BS*NA
#define NE 8
#define NAL 7
#define H 64
#define D_E 4356
#define D_A 4096
#define QTOT (NAGT*14)     // q output elements; hh follows at this offset

// ---------------- GEMM config ----------------
// C(4096 x 64) = Pcat(4096 x 2112) @ Wbig(2112 x 64), split-K
#define KPAD 2112
#define SPLITS 11
#define KSPL 192           // KPAD / SPLITS
#define BK 64
#define BM 64

// ---------------- workspace layout (float offsets) ----------------
#define WBIG_OFF 0
#define WBIG_SZ (KPAD*64)                 // 135168
#define PCAT_OFF (WBIG_OFF + WBIG_SZ)
#define PCAT_SZ (NAGT*KPAD)               // 8650752
#define RELU_OFF (PCAT_OFF + PCAT_SZ)
#define RELU_SZ (NAGT*NE*64)              // 2097152
#define CPART_OFF (RELU_OFF + RELU_SZ)
#define CPART_SZ (SPLITS*NAGT*64)         // 2883584
#define WIHT_OFF (CPART_OFF + CPART_SZ)
#define WIHT_SZ (64*192)                  // 12288
#define WHHT_OFF (WIHT_OFF + WIHT_SZ)
#define WATT_OFF (WHHT_OFF + WIHT_SZ)
#define WATTB_OFF (WATT_OFF + 4096)
#define BATTT_OFF (WATTB_OFF + 64)
#define BATT0_OFF (BATTT_OFF + 64)
// total ~13.8M floats = ~55 MB of d_ws

#define PREP_ITEMS (WBIG_SZ + 2*WIHT_SZ + 4096 + 64 + 64 + 1)  // 163969
#define PREP_BLOCKS ((PREP_ITEMS + 255)/256)                   // 641
#define ENT_BLOCKS (NAGT/4)                                    // 1024

__device__ __forceinline__ float dot4w(const float* __restrict__ p,
                                       const float* __restrict__ wim, int h) {
    return p[0]*wim[h] + p[1]*wim[64+h] + p[2]*wim[128+h] + p[3]*wim[192+h];
}

// ============================================================
// Kernel A: weight prep (fold w_in_merge / w_out_merge, transposes)
//           + per-agent entity phase (relu_e, P outer-products)
// ============================================================
__global__ __launch_bounds__(256) void k_prep_entity(
    const float* __restrict__ own,  const float* __restrict__ ef,
    const float* __restrict__ af,   const float* __restrict__ hew1,
    const float* __restrict__ heb1, const float* __restrict__ hew2,
    const float* __restrict__ heb2, const float* __restrict__ haw1,
    const float* __restrict__ hab1, const float* __restrict__ haw2,
    const float* __restrict__ hab2, const float* __restrict__ wim,
    const float* __restrict__ wih,  const float* __restrict__ whh,
    const float* __restrict__ wom,  const float* __restrict__ fc1w,
    float* __restrict__ ws)
{
    int bid = blockIdx.x;
    if (bid < PREP_BLOCKS) {
        int idx = bid*256 + threadIdx.x;
        if (idx >= PREP_ITEMS) return;
        if (idx < WBIG_SZ) {
            // Wbig rows: [0,1024) Wm_e(f*64+j), [1024,2048) Wm_a,
            // [2048,2064) Bm_e(f), [2064,2080) Bm_a(f), [2080,2096) fc1_w, pad 0
            int rr = idx >> 6, h = idx & 63;
            float s;
            if (rr < 1024) {
                int f = rr >> 6, j = rr & 63;
                s = dot4w(hew2 + (size_t)j*D_E + f*256 + h*4, wim, h);
            } else if (rr < 2048) {
                int r2 = rr - 1024; int f = r2 >> 6, j = r2 & 63;
                s = dot4w(haw2 + (size_t)j*D_A + f*256 + h*4, wim, h);
            } else if (rr < 2064) {
                int f = rr - 2048;
                s = dot4w(heb2 + f*256 + h*4, wim, h);
            } else if (rr < 2080) {
                int f = rr - 2064;
                s = dot4w(hab2 + f*256 + h*4, wim, h);
            } else if (rr < 2096) {
                int f = rr - 2080;
                s = fc1w[f*64 + h];
            } else {
                s = 0.f;
            }
            ws[WBIG_OFF + idx] = s;
            return;
        }
        int k2 = idx - WBIG_SZ;
        if (k2 < WIHT_SZ) {                       // WihT[h*192+c] = wih[c*64+h]
            int h = k2 / 192, c = k2 % 192;
            ws[WIHT_OFF + k2] = wih[c*64 + h];
            return;
        }
        k2 -= WIHT_SZ;
        if (k2 < WIHT_SZ) {
            int h = k2 / 192, c = k2 % 192;
            ws[WHHT_OFF + k2] = whh[c*64 + h];
            return;
        }
        k2 -= WIHT_SZ;
        if (k2 < 4096) {                          // WattT[h*64+j]
            int h = k2 >> 6, j = k2 & 63;
            float s = 0.f;
            #pragma unroll
            for (int k = 0; k < 4; k++)
                s = fmaf(wom[k], hew2[(size_t)j*D_E + 4096 + h*4 + k], s);
            ws[WATT_OFF + k2] = s;
            return;
        }
        k2 -= 4096;
        if (k2 < 64) {                            // wattb[j]
            int j = k2;
            float s = 0.f;
            #pragma unroll
            for (int k = 0; k < 4; k++)
                s = fmaf(wom[k], hew2[(size_t)j*D_E + 4352 + k], s);
            ws[WATTB_OFF + j] = s;
            return;
        }
        k2 -= 64;
        if (k2 < 64) {                            // battT[h]
            int h = k2;
            float s = 0.f;
            #pragma unroll
            for (int k = 0; k < 4; k++)
                s = fmaf(wom[k], heb2[4096 + h*4 + k], s);
            ws[BATTT_OFF + h] = s;
            return;
        }
        {                                         // batt0
            float s = 0.f;
            #pragma unroll
            for (int k = 0; k < 4; k++) s = fmaf(wom[k], heb2[4352 + k], s);
            ws[BATT0_OFF] = s;
        }
        return;
    }

    // ---------------- entity phase: one wave per agent n ----------------
    int t = threadIdx.x, w = t >> 6, l = t & 63;
    int n = (bid - PREP_BLOCKS)*4 + w;
    float* pc = ws + PCAT_OFF + (size_t)n*KPAD;

    // enemies
    {
        float Pe[16];
        #pragma unroll
        for (int f = 0; f < 16; f++) Pe[f] = 0.f;
        float se = 0.f;
        for (int e = 0; e < NE; e++) {
            int m = n*NE + e;
            float val = ef[(size_t)m*16 + (l & 15)];
            float ff[16];
            #pragma unroll
            for (int f = 0; f < 16; f++) ff[f] = __shfl(val, f);
            float acc = heb1[l];
            #pragma unroll
            for (int f = 0; f < 16; f++) acc = fmaf(ff[f], hew1[f*64 + l], acc);
            float r = fmaxf(acc, 0.f);
            ws[RELU_OFF + (size_t)m*64 + l] = r;
            #pragma unroll
            for (int f = 0; f < 16; f++) Pe[f] = fmaf(ff[f], r, Pe[f]);
            se += val;
        }
        #pragma unroll
        for (int f = 0; f < 16; f++) pc[f*64 + l] = Pe[f];
        if (l < 16) pc[2048 + l] = se;
    }
    // allies
    {
        float Pa[16];
        #pragma unroll
        for (int f = 0; f < 16; f++) Pa[f] = 0.f;
        float sa = 0.f;
        for (int a = 0; a < NAL; a++) {
            int m = n*NAL + a;
            float val = af[(size_t)m*16 + (l & 15)];
            float ff[16];
            #pragma unroll
            for (int f = 0; f < 16; f++) ff[f] = __shfl(val, f);
            float acc = hab1[l];
            #pragma unroll
            for (int f = 0; f < 16; f++) acc = fmaf(ff[f], haw1[f*64 + l], acc);
            float r = fmaxf(acc, 0.f);
            #pragma unroll
            for (int f = 0; f < 16; f++) Pa[f] = fmaf(ff[f], r, Pa[f]);
            sa += val;
        }
        #pragma unroll
        for (int f = 0; f < 16; f++) pc[1024 + f*64 + l] = Pa[f];
        if (l < 16) pc[2064 + l] = sa;
    }
    if (l < 16) pc[2080 + l] = own[(size_t)n*16 + l];
    if (l < 16) pc[2096 + l] = 0.f;
}

// ============================================================
// Kernel B: split-K GEMM  Cpart[sp] += Pcat(64-row tile) @ Wbig
// ============================================================
__global__ __launch_bounds__(256) void k_gemm(const float* __restrict__ wsr,
                                              float* __restrict__ wsw)
{
    __shared__ float As[BK][BM + 4];   // [64][68] transposed A tile (pad vs bank conflicts)
    __shared__ float Bs[BK][64];
    int t = threadIdx.x;
    int mt = blockIdx.x / SPLITS;
    int sp = blockIdx.x % SPLITS;
    int n0 = mt * BM;
    const float* A = wsr + PCAT_OFF;
    const float* B = wsr + WBIG_OFF;
    float acc[4][4] = {{0.f}};
    int i = t & 15, jq = t >> 4;

    for (int ch = 0; ch < KSPL/BK; ch++) {        // 3 chunks
        int kb = sp*KSPL + ch*BK;
        #pragma unroll
        for (int li = 0; li < 4; li++) {          // stage A (transpose into LDS)
            int idx = t + li*256;
            int r = idx >> 4, c = idx & 15;
            float4 v = *(const float4*)(A + (size_t)(n0 + r)*KPAD + kb + c*4);
            As[c*4 + 0][r] = v.x; As[c*4 + 1][r] = v.y;
            As[c*4 + 2][r] = v.z; As[c*4 + 3][r] = v.w;
        }
        #pragma unroll
        for (int li = 0; li < 4; li++) {          // stage B
            int idx = t + li*256;
            int r = idx >> 4, c = idx & 15;
            *(float4*)&Bs[r][c*4] = *(const float4*)(B + (size_t)(kb + r)*64 + c*4);
        }
        __syncthreads();
        #pragma unroll 16
        for (int kk = 0; kk < BK; kk++) {
            float4 a4 = *(const float4*)&As[kk][i*4];
            float4 b4 = *(const float4*)&Bs[kk][jq*4];
            float av[4] = {a4.x, a4.y, a4.z, a4.w};
            float bv[4] = {b4.x, b4.y, b4.z, b4.w};
            #pragma unroll
            for (int r = 0; r < 4; r++)
                #pragma unroll
                for (int c = 0; c < 4; c++)
                    acc[r][c] = fmaf(av[r], bv[c], acc[r][c]);
        }
        __syncthreads();
    }
    float* C = wsw + CPART_OFF + (size_t)sp*(NAGT*64);
    #pragma unroll
    for (int qi = 0; qi < 4; qi++) {
        float4 st = make_float4(acc[qi][0], acc[qi][1], acc[qi][2], acc[qi][3]);
        *(float4*)(C + (size_t)(n0 + i*4 + qi)*64 + jq*4) = st;
    }
}

// ============================================================
// Kernel C: epilogue — reduce split-K, +fc1_b, ReLU, GRU, Q heads
// one wave handles 4 agents; block = 4 waves = 16 agents
// ============================================================
__global__ __launch_bounds__(256) void k_epilogue(
    const float* __restrict__ hidden, const float* __restrict__ fc1b,
    const float* __restrict__ gbih,   const float* __restrict__ gbhh,
    const float* __restrict__ fc2w,   const float* __restrict__ fc2b,
    const float* __restrict__ ws,     float* __restrict__ out)
{
    __shared__ float lX[4][4][64], lH[4][4][64], lHH[4][4][64], lU[4][4][64];
    int t = threadIdx.x, w = t >> 6, j = t & 63;
    int n0 = (blockIdx.x*4 + w)*4;
    const float* Cp = ws + CPART_OFF;

    float hid[4];
    #pragma unroll
    for (int q = 0; q < 4; q++) {
        int n = n0 + q;
        float emb = fc1b[j];
        #pragma unroll
        for (int sp = 0; sp < SPLITS; sp++)
            emb += Cp[(size_t)sp*(NAGT*64) + (size_t)n*64 + j];
        float xv = fmaxf(emb, 0.f);
        lX[w][q][j] = xv;
        float hv = hidden[(size_t)n*64 + j];
        hid[q] = hv; lH[w][q][j] = hv;
    }
    __syncthreads();

    // GRU: lane j owns channel j of r/z/g for 4 agents
    float gir[4], giz[4], gig[4], ghr[4], ghz[4], ghg[4];
    #pragma unroll
    for (int q = 0; q < 4; q++) {
        gir[q] = gbih[j]; giz[q] = gbih[64 + j]; gig[q] = gbih[128 + j];
        ghr[q] = gbhh[j]; ghz[q] = gbhh[64 + j]; ghg[q] = gbhh[128 + j];
    }
    const float* WihT = ws + WIHT_OFF;
    const float* WhhT = ws + WHHT_OFF;
    #pragma unroll 8
    for (int h = 0; h < 64; h++) {
        float wri = WihT[h*192 + j], wzi = WihT[h*192 + 64 + j], wgi = WihT[h*192 + 128 + j];
        float wrh = WhhT[h*192 + j], wzh = WhhT[h*192 + 64 + j], wgh = WhhT[h*192 + 128 + j];
        #pragma unroll
        for (int q = 0; q < 4; q++) {
            float xv = lX[w][q][h], hv = lH[w][q][h];
            gir[q] = fmaf(xv, wri, gir[q]); giz[q] = fmaf(xv, wzi, giz[q]);
            gig[q] = fmaf(xv, wgi, gig[q]);
            ghr[q] = fmaf(hv, wrh, ghr[q]); ghz[q] = fmaf(hv, wzh, ghz[q]);
            ghg[q] = fmaf(hv, wgh, ghg[q]);
        }
    }
    #pragma unroll
    for (int q = 0; q < 4; q++) {
        float r = 1.f/(1.f + expf(-(gir[q] + ghr[q])));
        float z = 1.f/(1.f + expf(-(giz[q] + ghz[q])));
        float g = tanhf(gig[q] + r*ghg[q]);
        float hv = (1.f - z)*g + z*hid[q];
        lHH[w][q][j] = hv;
        out[QTOT + (size_t)(n0 + q)*64 + j] = hv;
    }
    __syncthreads();

    // attack-Q: u[n,j] = sum_h hh*WattT + wattb;  cb = sum_h hh*battT + batt0
    const float* WattT = ws + WATT_OFF;
    float b0 = ws[BATT0_OFF];
    float u[4], cb[4];
    #pragma unroll
    for (int q = 0; q < 4; q++) { u[q] = ws[WATTB_OFF + j]; cb[q] = b0; }
    #pragma unroll 8
    for (int h = 0; h < 64; h++) {
        float wa = WattT[h*64 + j];
        float bt = ws[BATTT_OFF + h];
        #pragma unroll
        for (int q = 0; q < 4; q++) {
            float hv = lHH[w][q][h];
            u[q]  = fmaf(hv, wa, u[q]);
            cb[q] = fmaf(hv, bt, cb[q]);
        }
    }
    #pragma unroll
    for (int q = 0; q < 4; q++) lU[w][q][j] = u[q];
    __syncthreads();

    // q_attack[n,e] = sum_j relu_e[ne,j]*u[n,j] + cb ; lanes = (e, p) 8x8
    int e = j >> 3, p = j & 7;
    #pragma unroll
    for (int q = 0; q < 4; q++) {
        int n = n0 + q, m = n*NE + e;
        const float* rl = ws + RELU_OFF + (size_t)m*64 + p*8;
        float4 r0 = *(const float4*)(rl);
        float4 r1 = *(const float4*)(rl + 4);
        float s = 0.f;
        s = fmaf(r0.x, lU[w][q][p*8 + 0], s); s = fmaf(r0.y, lU[w][q][p*8 + 1], s);
        s = fmaf(r0.z, lU[w][q][p*8 + 2], s); s = fmaf(r0.w, lU[w][q][p*8 + 3], s);
        s = fmaf(r1.x, lU[w][q][p*8 + 4], s); s = fmaf(r1.y, lU[w][q][p*8 + 5], s);
        s = fmaf(r1.z, lU[w][q][p*8 + 6], s); s = fmaf(r1.w, lU[w][q][p*8 + 7], s);
        s += __shfl_xor(s, 1); s += __shfl_xor(s, 2); s += __shfl_xor(s, 4);
        if (p == 0) out[(size_t)n*14 + 6 + e] = s + cb[q];
    }
    // q_normal: 24 lanes cover (q,o) pairs
    if (j < 24) {
        int q = j / 6, o = j % 6;
        float qn = fc2b[o];
        #pragma unroll 8
        for (int h = 0; h < 64; h++) qn = fmaf(lHH[w][q][h], fc2w[h*6 + o], qn);
        out[(size_t)(n0 + q)*14 + o] = qn;
    }
}

// ============================================================
extern "C" void kernel_launch(void* const* d_in, const int* in_sizes, int n_in,
                              void* d_out, int out_size, void* d_ws, size_t ws_size,
                              hipStream_t stream) {
    const float* own   = (const float*)d_in[0];
    const float* ef    = (const float*)d_in[1];
    const float* af    = (const float*)d_in[2];
    const float* hidden= (const float*)d_in[3];
    const float* fc1w  = (const float*)d_in[4];
    const float* fc1b  = (const float*)d_in[5];
    const float* hew1  = (const float*)d_in[6];
    const float* heb1  = (const float*)d_in[7];
    const float* hew2  = (const float*)d_in[8];
    const float* heb2  = (const float*)d_in[9];
    const float* haw1  = (const float*)d_in[10];
    const float* hab1  = (const float*)d_in[11];
    const float* haw2  = (const float*)d_in[12];
    const float* hab2  = (const float*)d_in[13];
    const float* wim   = (const float*)d_in[14];
    const float* wih   = (const float*)d_in[15];
    const float* gbih  = (const float*)d_in[16];
    const float* whh   = (const float*)d_in[17];
    const float* gbhh  = (const float*)d_in[18];
    const float* fc2w  = (const float*)d_in[19];
    const float* fc2b  = (const float*)d_in[20];
    const float* wom   = (const float*)d_in[21];
    float* out = (float*)d_out;
    float* ws  = (float*)d_ws;

    k_prep_entity<<<PREP_BLOCKS + ENT_BLOCKS, 256, 0, stream>>>(
        own, ef, af, hew1, heb1, hew2, heb2, haw1, hab1, haw2, hab2,
        wim, wih, whh, wom, fc1w, ws);
    k_gemm<<<(NAGT/BM)*SPLITS, 256, 0, stream>>>(ws, ws);
    k_epilogue<<<NAGT/16, 256, 0, stream>>>(hidden, fc1b, gbih, gbhh,
                                            fc2w, fc2b, ws, out);
}

// Round 2
// 155.764 us; speedup vs baseline: 1.0469x; 1.0469x over previous
//
#include <hip/hip_runtime.h>
#include <math.h>

// ---------------- problem constants ----------------
#define NAGT 4096          // BS*NA
#define NE 8
#define NAL 7
#define H 64
#define D_E 4356
#define D_A 4096
#define QTOT (NAGT*14)     // q output elements; hh follows at this offset

// ---------------- GEMM config ----------------
// C(4096 x 64) = Pcat(4096 x 2112) @ Wbig(2112 x 64), split-K
#define KPAD 2112
#define SPLITS 11
#define KSPL 192           // KPAD / SPLITS
#define BK 64
#define BM 64

// ---------------- workspace layout (float offsets) ----------------
#define WBIG_OFF 0
#define WBIG_SZ (KPAD*64)                 // 135168
#define PCAT_OFF (WBIG_OFF + WBIG_SZ)
#define PCAT_SZ (NAGT*KPAD)               // 8650752
#define RELU_OFF (PCAT_OFF + PCAT_SZ)
#define RELU_SZ (NAGT*NE*64)              // 2097152
#define CPART_OFF (RELU_OFF + RELU_SZ)
#define CPART_SZ (SPLITS*NAGT*64)         // 2883584
#define WIHT_OFF (CPART_OFF + CPART_SZ)
#define WIHT_SZ (64*192)                  // 12288
#define WHHT_OFF (WIHT_OFF + WIHT_SZ)
#define WATT_OFF (WHHT_OFF + WIHT_SZ)
#define WATTB_OFF (WATT_OFF + 4096)
#define BATTT_OFF (WATTB_OFF + 64)
#define BATT0_OFF (BATTT_OFF + 64)

#define PREP_ITEMS (WBIG_SZ + 2*WIHT_SZ + 4096 + 64 + 64 + 1)  // 163969
#define PREP_BLOCKS ((PREP_ITEMS + 255)/256)                   // 641
#define ENT_BLOCKS (NAGT/4)                                    // 1024

__device__ __forceinline__ float dot4w(const float* __restrict__ p,
                                       const float* __restrict__ wim, int h) {
    return p[0]*wim[h] + p[1]*wim[64+h] + p[2]*wim[128+h] + p[3]*wim[192+h];
}

// ============================================================
// Kernel A: weight prep (fold w_in_merge / w_out_merge, transposes)
//           + per-agent entity phase (relu_e, P outer-products)
// (unchanged from R1 — passed; structurally sound)
// ============================================================
__global__ __launch_bounds__(256) void k_prep_entity(
    const float* __restrict__ own,  const float* __restrict__ ef,
    const float* __restrict__ af,   const float* __restrict__ hew1,
    const float* __restrict__ heb1, const float* __restrict__ hew2,
    const float* __restrict__ heb2, const float* __restrict__ haw1,
    const float* __restrict__ hab1, const float* __restrict__ haw2,
    const float* __restrict__ hab2, const float* __restrict__ wim,
    const float* __restrict__ wih,  const float* __restrict__ whh,
    const float* __restrict__ wom,  const float* __restrict__ fc1w,
    float* __restrict__ ws)
{
    int bid = blockIdx.x;
    if (bid < PREP_BLOCKS) {
        int idx = bid*256 + threadIdx.x;
        if (idx >= PREP_ITEMS) return;
        if (idx < WBIG_SZ) {
            int rr = idx >> 6, h = idx & 63;
            float s;
            if (rr < 1024) {
                int f = rr >> 6, j = rr & 63;
                s = dot4w(hew2 + (size_t)j*D_E + f*256 + h*4, wim, h);
            } else if (rr < 2048) {
                int r2 = rr - 1024; int f = r2 >> 6, j = r2 & 63;
                s = dot4w(haw2 + (size_t)j*D_A + f*256 + h*4, wim, h);
            } else if (rr < 2064) {
                int f = rr - 2048;
                s = dot4w(heb2 + f*256 + h*4, wim, h);
            } else if (rr < 2080) {
                int f = rr - 2064;
                s = dot4w(hab2 + f*256 + h*4, wim, h);
            } else if (rr < 2096) {
                int f = rr - 2080;
                s = fc1w[f*64 + h];
            } else {
                s = 0.f;
            }
            ws[WBIG_OFF + idx] = s;
            return;
        }
        int k2 = idx - WBIG_SZ;
        if (k2 < WIHT_SZ) {
            int h = k2 / 192, c = k2 % 192;
            ws[WIHT_OFF + k2] = wih[c*64 + h];
            return;
        }
        k2 -= WIHT_SZ;
        if (k2 < WIHT_SZ) {
            int h = k2 / 192, c = k2 % 192;
            ws[WHHT_OFF + k2] = whh[c*64 + h];
            return;
        }
        k2 -= WIHT_SZ;
        if (k2 < 4096) {
            int h = k2 >> 6, j = k2 & 63;
            float s = 0.f;
            #pragma unroll
            for (int k = 0; k < 4; k++)
                s = fmaf(wom[k], hew2[(size_t)j*D_E + 4096 + h*4 + k], s);
            ws[WATT_OFF + k2] = s;
            return;
        }
        k2 -= 4096;
        if (k2 < 64) {
            int j = k2;
            float s = 0.f;
            #pragma unroll
            for (int k = 0; k < 4; k++)
                s = fmaf(wom[k], hew2[(size_t)j*D_E + 4352 + k], s);
            ws[WATTB_OFF + j] = s;
            return;
        }
        k2 -= 64;
        if (k2 < 64) {
            int h = k2;
            float s = 0.f;
            #pragma unroll
            for (int k = 0; k < 4; k++)
                s = fmaf(wom[k], heb2[4096 + h*4 + k], s);
            ws[BATTT_OFF + h] = s;
            return;
        }
        {
            float s = 0.f;
            #pragma unroll
            for (int k = 0; k < 4; k++) s = fmaf(wom[k], heb2[4352 + k], s);
            ws[BATT0_OFF] = s;
        }
        return;
    }

    // ---------------- entity phase: one wave per agent n ----------------
    int t = threadIdx.x, w = t >> 6, l = t & 63;
    int n = (bid - PREP_BLOCKS)*4 + w;
    float* pc = ws + PCAT_OFF + (size_t)n*KPAD;

    // enemies
    {
        float Pe[16];
        #pragma unroll
        for (int f = 0; f < 16; f++) Pe[f] = 0.f;
        float se = 0.f;
        for (int e = 0; e < NE; e++) {
            int m = n*NE + e;
            float val = ef[(size_t)m*16 + (l & 15)];
            float ff[16];
            #pragma unroll
            for (int f = 0; f < 16; f++) ff[f] = __shfl(val, f);
            float acc = heb1[l];
            #pragma unroll
            for (int f = 0; f < 16; f++) acc = fmaf(ff[f], hew1[f*64 + l], acc);
            float r = fmaxf(acc, 0.f);
            ws[RELU_OFF + (size_t)m*64 + l] = r;
            #pragma unroll
            for (int f = 0; f < 16; f++) Pe[f] = fmaf(ff[f], r, Pe[f]);
            se += val;
        }
        #pragma unroll
        for (int f = 0; f < 16; f++) pc[f*64 + l] = Pe[f];
        if (l < 16) pc[2048 + l] = se;
    }
    // allies
    {
        float Pa[16];
        #pragma unroll
        for (int f = 0; f < 16; f++) Pa[f] = 0.f;
        float sa = 0.f;
        for (int a = 0; a < NAL; a++) {
            int m = n*NAL + a;
            float val = af[(size_t)m*16 + (l & 15)];
            float ff[16];
            #pragma unroll
            for (int f = 0; f < 16; f++) ff[f] = __shfl(val, f);
            float acc = hab1[l];
            #pragma unroll
            for (int f = 0; f < 16; f++) acc = fmaf(ff[f], haw1[f*64 + l], acc);
            float r = fmaxf(acc, 0.f);
            #pragma unroll
            for (int f = 0; f < 16; f++) Pa[f] = fmaf(ff[f], r, Pa[f]);
            sa += val;
        }
        #pragma unroll
        for (int f = 0; f < 16; f++) pc[1024 + f*64 + l] = Pa[f];
        if (l < 16) pc[2064 + l] = sa;
    }
    if (l < 16) pc[2080 + l] = own[(size_t)n*16 + l];
    if (l < 16) pc[2096 + l] = 0.f;
}

// ============================================================
// Kernel B: split-K GEMM, XOR-swizzled A tile (2-way stores+reads)
// Layout: element (k, m) lives at As[k][ 4*((m>>2)^(k>>2)) + (m&3) ]
// ============================================================
__global__ __launch_bounds__(256) void k_gemm(const float* __restrict__ wsr,
                                              float* __restrict__ wsw)
{
    __shared__ float As[BK][68];
    __shared__ float Bs[BK][68];
    int t = threadIdx.x;
    int mt = blockIdx.x / SPLITS;
    int sp = blockIdx.x % SPLITS;
    int n0 = mt * BM;
    const float* A = wsr + PCAT_OFF;
    const float* B = wsr + WBIG_OFF;
    float acc[4][4] = {{0.f}};
    int i = t & 15, jq = t >> 4;

    for (int ch = 0; ch < KSPL/BK; ch++) {        // 3 chunks
        int kb = sp*KSPL + ch*BK;
        #pragma unroll
        for (int li = 0; li < 4; li++) {
            int idx = t + li*256;
            int r = idx >> 4, c = idx & 15;       // r = m-row, c = k-group
            float4 v = *(const float4*)(A + (size_t)(n0 + r)*KPAD + kb + c*4);
            int col = ((((r >> 2) ^ c) & 15) << 2) | (r & 3);
            As[c*4 + 0][col] = v.x; As[c*4 + 1][col] = v.y;
            As[c*4 + 2][col] = v.z; As[c*4 + 3][col] = v.w;
            float4 bv = *(const float4*)(B + (size_t)(kb + r)*64 + c*4);
            *(float4*)&Bs[r][c*4] = bv;
        }
        __syncthreads();
        #pragma unroll 16
        for (int kk = 0; kk < BK; kk++) {
            int ga = ((i ^ (kk >> 2)) & 15) << 2;
            float4 a4 = *(const float4*)&As[kk][ga];
            float4 b4 = *(const float4*)&Bs[kk][jq*4];
            float av[4] = {a4.x, a4.y, a4.z, a4.w};
            float bv[4] = {b4.x, b4.y, b4.z, b4.w};
            #pragma unroll
            for (int r = 0; r < 4; r++)
                #pragma unroll
                for (int c = 0; c < 4; c++)
                    acc[r][c] = fmaf(av[r], bv[c], acc[r][c]);
        }
        __syncthreads();
    }
    float* C = wsw + CPART_OFF + (size_t)sp*(NAGT*64);
    #pragma unroll
    for (int qi = 0; qi < 4; qi++) {
        float4 st = make_float4(acc[qi][0], acc[qi][1], acc[qi][2], acc[qi][3]);
        *(float4*)(C + (size_t)(n0 + i*4 + qi)*64 + jq*4) = st;
    }
}

// ============================================================
// Kernel C: epilogue — split-K reduce, ReLU, GRU, Q heads
// 2 agents per wave, 512 blocks (2 blocks/CU, 2 waves/SIMD).
// All LDS is wave-private ([w][...]) -> NO barriers needed.
// ============================================================
__global__ __launch_bounds__(256) void k_epilogue(
    const float* __restrict__ hidden, const float* __restrict__ fc1b,
    const float* __restrict__ gbih,   const float* __restrict__ gbhh,
    const float* __restrict__ fc2w,   const float* __restrict__ fc2b,
    const float* __restrict__ ws,     float* __restrict__ out)
{
    __shared__ float lX[4][2][64], lH[4][2][64], lHH[4][2][64], lU[4][2][64];
    int t = threadIdx.x, w = t >> 6, j = t & 63;
    int n0 = (blockIdx.x*4 + w)*2;
    const float* Cp = ws + CPART_OFF;

    float hid[2];
    #pragma unroll
    for (int q = 0; q < 2; q++) {
        int n = n0 + q;
        float emb = fc1b[j];
        #pragma unroll
        for (int sp = 0; sp < SPLITS; sp++)
            emb += Cp[(size_t)sp*(NAGT*64) + (size_t)n*64 + j];
        float xv = fmaxf(emb, 0.f);
        lX[w][q][j] = xv;
        float hv = hidden[(size_t)n*64 + j];
        hid[q] = hv; lH[w][q][j] = hv;
    }
    // wave-private LDS: compiler's lgkmcnt ordering suffices, no barrier

    float gir[2], giz[2], gig[2], ghr[2], ghz[2], ghg[2];
    #pragma unroll
    for (int q = 0; q < 2; q++) {
        gir[q] = gbih[j]; giz[q] = gbih[64 + j]; gig[q] = gbih[128 + j];
        ghr[q] = gbhh[j]; ghz[q] = gbhh[64 + j]; ghg[q] = gbhh[128 + j];
    }
    const float* WihT = ws + WIHT_OFF;
    const float* WhhT = ws + WHHT_OFF;
    #pragma unroll 8
    for (int h = 0; h < 64; h++) {
        float wri = WihT[h*192 + j], wzi = WihT[h*192 + 64 + j], wgi = WihT[h*192 + 128 + j];
        float wrh = WhhT[h*192 + j], wzh = WhhT[h*192 + 64 + j], wgh = WhhT[h*192 + 128 + j];
        #pragma unroll
        for (int q = 0; q < 2; q++) {
            float xv = lX[w][q][h], hv = lH[w][q][h];
            gir[q] = fmaf(xv, wri, gir[q]); giz[q] = fmaf(xv, wzi, giz[q]);
            gig[q] = fmaf(xv, wgi, gig[q]);
            ghr[q] = fmaf(hv, wrh, ghr[q]); ghz[q] = fmaf(hv, wzh, ghz[q]);
            ghg[q] = fmaf(hv, wgh, ghg[q]);
        }
    }
    #pragma unroll
    for (int q = 0; q < 2; q++) {
        float r = 1.f/(1.f + expf(-(gir[q] + ghr[q])));
        float z = 1.f/(1.f + expf(-(giz[q] + ghz[q])));
        float g = tanhf(gig[q] + r*ghg[q]);
        float hv = (1.f - z)*g + z*hid[q];
        lHH[w][q][j] = hv;
        out[QTOT + (size_t)(n0 + q)*64 + j] = hv;
    }

    // attack-Q precursors: u[n,j] = sum_h hh*Watt[h,j] + wattb[j]; cb = sum_h hh*battT + batt0
    const float* WattT = ws + WATT_OFF;
    float b0 = ws[BATT0_OFF];
    float u[2], cb[2];
    #pragma unroll
    for (int q = 0; q < 2; q++) { u[q] = ws[WATTB_OFF + j]; cb[q] = b0; }
    #pragma unroll 8
    for (int h = 0; h < 64; h++) {
        float wa = WattT[h*64 + j];
        float bt = ws[BATTT_OFF + h];
        #pragma unroll
        for (int q = 0; q < 2; q++) {
            float hv = lHH[w][q][h];
            u[q]  = fmaf(hv, wa, u[q]);
            cb[q] = fmaf(hv, bt, cb[q]);
        }
    }
    #pragma unroll
    for (int q = 0; q < 2; q++) lU[w][q][j] = u[q];

    // q_attack[n,e] = sum_j relu_e[ne,j]*u[n,j] + cb ; lanes = (e, p) 8x8
    int e = j >> 3, p = j & 7;
    #pragma unroll
    for (int q = 0; q < 2; q++) {
        int n = n0 + q, m = n*NE + e;
        const float* rl = ws + RELU_OFF + (size_t)m*64 + p*8;
        float4 r0 = *(const float4*)(rl);
        float4 r1 = *(const float4*)(rl + 4);
        float s = 0.f;
        s = fmaf(r0.x, lU[w][q][p*8 + 0], s); s = fmaf(r0.y, lU[w][q][p*8 + 1], s);
        s = fmaf(r0.z, lU[w][q][p*8 + 2], s); s = fmaf(r0.w, lU[w][q][p*8 + 3], s);
        s = fmaf(r1.x, lU[w][q][p*8 + 4], s); s = fmaf(r1.y, lU[w][q][p*8 + 5], s);
        s = fmaf(r1.z, lU[w][q][p*8 + 6], s); s = fmaf(r1.w, lU[w][q][p*8 + 7], s);
        s += __shfl_xor(s, 1); s += __shfl_xor(s, 2); s += __shfl_xor(s, 4);
        if (p == 0) out[(size_t)n*14 + 6 + e] = s + cb[q];
    }
    // q_normal: 12 lanes cover (q,o) pairs
    if (j < 12) {
        int q = j / 6, o = j % 6;
        float qn = fc2b[o];
        #pragma unroll 8
        for (int h = 0; h < 64; h++) qn = fmaf(lHH[w][q][h], fc2w[h*6 + o], qn);
        out[(size_t)(n0 + q)*14 + o] = qn;
    }
}

// ============================================================
extern "C" void kernel_launch(void* const* d_in, const int* in_sizes, int n_in,
                              void* d_out, int out_size, void* d_ws, size_t ws_size,
                              hipStream_t stream) {
    const float* own   = (const float*)d_in[0];
    const float* ef    = (const float*)d_in[1];
    const float* af    = (const float*)d_in[2];
    const float* hidden= (const float*)d_in[3];
    const float* fc1w  = (const float*)d_in[4];
    const float* fc1b  = (const float*)d_in[5];
    const float* hew1  = (const float*)d_in[6];
    const float* heb1  = (const float*)d_in[7];
    const float* hew2  = (const float*)d_in[8];
    const float* heb2  = (const float*)d_in[9];
    const float* haw1  = (const float*)d_in[10];
    const float* hab1  = (const float*)d_in[11];
    const float* haw2  = (const float*)d_in[12];
    const float* hab2  = (const float*)d_in[13];
    const float* wim   = (const float*)d_in[14];
    const float* wih   = (const float*)d_in[15];
    const float* gbih  = (const float*)d_in[16];
    const float* whh   = (const float*)d_in[17];
    const float* gbhh  = (const float*)d_in[18];
    const float* fc2w  = (const float*)d_in[19];
    const float* fc2b  = (const float*)d_in[20];
    const float* wom   = (const float*)d_in[21];
    float* out = (float*)d_out;
    float* ws  = (float*)d_ws;

    k_prep_entity<<<PREP_BLOCKS + ENT_BLOCKS, 256, 0, stream>>>(
        own, ef, af, hew1, heb1, hew2, heb2, haw1, hab1, haw2, hab2,
        wim, wih, whh, wom, fc1w, ws);
    k_gemm<<<(NAGT/BM)*SPLITS, 256, 0, stream>>>(ws, ws);
    k_epilogue<<<NAGT/8, 256, 0, stream>>>(hidden, fc1b, gbih, gbhh,
                                           fc2w, fc2b, ws, out);
}